// Round 2
// baseline (803.205 us; speedup 1.0000x reference)
//
#include <hip/hip_runtime.h>

// DirectionalFilterBank: 3-level binary tree of (shear ±1 -> depthwise 9x9 conv).
// shear(x,s)[h,w] = 0.5*(x[h,c0]+x[h,c0+1]), c0 = w + s*h + (s>0 ? -128 : 127),
// defined on w in [0,256); conv zero-pads the SHEARED image by 4 on all sides.
// Filter is rank-2 separable: filt_c = -(A (x) A) + (B (x) B) [+ center delta, c==0].
//
// R3 geometry: TH=32, TW=256, serial-14 schedule (keeps 64MB producer->consumer
// pairs L3-resident; batching thrashed L3).
// R1: wave-per-row vectorized staging (f4 loads, <=1 divergent lane/row): 912->590us.
//
// THIS ROUND: kernel is LATENCY-bound, not issue-bound. Evidence: R1 removed
// ~6.7us/conv of issue time but saved 23us/conv (3.4x amplification). Floors:
// VALU issue ~7.3us, LDS ~7.7us, memory ~3TB/s -- nothing saturated at 42us/conv.
// Cause: 41.25KB LDS -> 3 blocks/CU -> only 3 waves/SIMD behind a barrier-split
// kernel. Fix: 512 threads/block, SAME tile/LDS/traffic -> 24 waves/CU (6/SIMD).
// Per-thread: staging 5 u-iters (8 waves x 5 rows), compute rg=tid>>6 owns 4 rows
// (window 12). +33% total FMA from horizontal redundancy -- absorbed by the 17%
// VALU utilization headroom.

#define B_ 4
#define C_ 64
#define H_ 256
#define W_ 256
#define TH 32                 // output rows per block
#define SROWS (TH + 8)        // 40 staged sheared rows
#define SCOLS (W_ + 8)        // 264 staged cols; LDS = 41.25 KiB
#define NPB 2048              // blocks per conv = 4*64*8

// 4-byte-aligned float4 view: shear offset makes global f4 loads dword- but not
// 16B-aligned. Compiler emits a legal unaligned dwordx4 (or split) load.
struct alignas(4) f4u { float x, y, z, w; };

__global__ __launch_bounds__(512) void shear_sepconv_kernel(
    const float* __restrict__ in, float* __restrict__ dst,
    const float* __restrict__ filt, int parity)
{
    __shared__ float s_sh[SROWS][SCOLS];

    const int tid  = threadIdx.x;
    const int bid  = (int)blockIdx.x;
    const int tile = bid & 7;            // H/TH = 8
    const int c    = (bid >> 3) & 63;    // C = 64
    const int b    = bid >> 9;
    const int h0   = tile * TH;
    const int sign = parity ? -1 : 1;
    const int off  = parity ? 127 : -128;

    const float* base = in + ((size_t)b * C_ + c) * (size_t)(H_ * W_);

    // ---- stage sheared rows h0-4 .. h0+35 ----
    // Wave w stages rows r = w + 8u, u = 0..4. Lane L produces sheared cols
    // 4L..4L+3 (stored at j = 4+4L) from x[c0..c0+4], c0 = off + sign*hr + 4L
    // (wave-uniform g = off + sign*hr). <=1 divergent lane per row.
    {
        const int wave = tid >> 6;       // 0..7
        const int lane = tid & 63;

        // halo cols j in [0,4) and [260,264) are always zero: 40 rows x 2 f4s
        if (tid < 80) {
            const int r = tid >> 1;
            *(float4*)&s_sh[r][(tid & 1) ? 260 : 0] = make_float4(0.f, 0.f, 0.f, 0.f);
        }

        #pragma unroll
        for (int u = 0; u < 5; ++u) {
            const int r  = wave + u * 8;
            const int hr = h0 + r - 4;
            float4 v = make_float4(0.f, 0.f, 0.f, 0.f);
            if ((unsigned)hr < 256u) {                       // wave-uniform
                const float* row = base + (size_t)hr * W_;
                const int c0 = off + sign * hr + lane * 4;
                if (c0 >= 0 && c0 <= 251) {                  // fast: fully interior
                    const f4u  a = *(const f4u*)(row + c0);
                    const float e = row[c0 + 4];
                    v.x = 0.5f * (a.x + a.y);
                    v.y = 0.5f * (a.y + a.z);
                    v.z = 0.5f * (a.z + a.w);
                    v.w = 0.5f * (a.w + e);
                } else if (c0 >= -4 && c0 < 256) {           // <=1 lane per row
                    float t0 = ((unsigned)(c0    ) < 256u) ? row[c0    ] : 0.f;
                    float t1 = ((unsigned)(c0 + 1) < 256u) ? row[c0 + 1] : 0.f;
                    float t2 = ((unsigned)(c0 + 2) < 256u) ? row[c0 + 2] : 0.f;
                    float t3 = ((unsigned)(c0 + 3) < 256u) ? row[c0 + 3] : 0.f;
                    float t4 = ((unsigned)(c0 + 4) < 256u) ? row[c0 + 4] : 0.f;
                    v.x = 0.5f * (t0 + t1);
                    v.y = 0.5f * (t1 + t2);
                    v.z = 0.5f * (t2 + t3);
                    v.w = 0.5f * (t3 + t4);
                }
                // else: fully outside -> zero
            }
            *(float4*)&s_sh[r][4 + lane * 4] = v;            // 16B-aligned
        }
    }

    // ---- separable factors from channel 1 (uniform; identical for all c) ----
    const float* f1 = filt + 81;
    const float A4  = sqrtf(fmaxf(-f1[4 * 9 + 4], 0.f));
    const float rA4 = 1.f / A4;
    const float A0  = -f1[0 * 9 + 4] * rA4;
    const float A2  = -f1[2 * 9 + 4] * rA4;
    const float A6  = -f1[6 * 9 + 4] * rA4;
    const float A8  = -f1[8 * 9 + 4] * rA4;
    const float B5  = sqrtf(fmaxf(f1[5 * 9 + 5], 0.f));
    const float rB5 = 1.f / B5;
    const float B1  = f1[1 * 9 + 5] * rB5;
    const float B3  = f1[3 * 9 + 5] * rB5;
    const float B7  = f1[7 * 9 + 5] * rB5;
    const float vc[9] = {-A0, B1, -A2, B3, -A4, B5, -A6, B7, -A8};

    __syncthreads();

    // ---- compute: 8 row-groups x 4 rows; thread = 4 cols x 4 rows (window 12) ----
    const int rg   = tid >> 6;           // 0..7 -> out rows rg*4 .. rg*4+3
    const int lane = tid & 63;
    const int w0   = lane * 4;

    float acc[4][4];
    #pragma unroll
    for (int i = 0; i < 4; ++i)
        #pragma unroll
        for (int j = 0; j < 4; ++j) acc[i][j] = 0.f;

    #pragma unroll
    for (int t = 0; t < 12; ++t) {       // staged rows rg*4 + t
        const int rr = rg * 4 + t;
        const float4 sa = *(const float4*)&s_sh[rr][w0];
        const float4 sb = *(const float4*)&s_sh[rr][w0 + 4];
        const float4 sc4 = *(const float4*)&s_sh[rr][w0 + 8];
        const float s[12] = {sa.x, sa.y, sa.z, sa.w,
                             sb.x, sb.y, sb.z, sb.w,
                             sc4.x, sc4.y, sc4.z, sc4.w};
        float ha[4], hb[4];
        #pragma unroll
        for (int j = 0; j < 4; ++j) {
            ha[j] = fmaf(A8, s[j + 8],
                    fmaf(A6, s[j + 6],
                    fmaf(A4, s[j + 4],
                    fmaf(A2, s[j + 2], A0 * s[j]))));
            hb[j] = fmaf(B7, s[j + 7],
                    fmaf(B5, s[j + 5],
                    fmaf(B3, s[j + 3], B1 * s[j + 1])));
        }
        #pragma unroll
        for (int i = 0; i < 4; ++i) {
            const int ky = t - i;        // compile-time after unroll
            if (ky >= 0 && ky < 9) {
                #pragma unroll
                for (int j = 0; j < 4; ++j) {
                    const float hv = (ky & 1) ? hb[j] : ha[j];
                    acc[i][j] = fmaf(vc[ky], hv, acc[i][j]);
                }
            }
        }
    }

    // channel-0 delta: += sheared image value at the output location
    if (c == 0) {
        #pragma unroll
        for (int i = 0; i < 4; ++i) {
            const float4 sv = *(const float4*)&s_sh[rg * 4 + i + 4][w0 + 4];
            acc[i][0] += sv.x; acc[i][1] += sv.y; acc[i][2] += sv.z; acc[i][3] += sv.w;
        }
    }

    float* optr = dst + (((size_t)b * C_ + c) * H_ + h0 + rg * 4) * (size_t)W_ + w0;
    #pragma unroll
    for (int i = 0; i < 4; ++i) {
        const float4 v = {acc[i][0], acc[i][1], acc[i][2], acc[i][3]};
        *(float4*)(optr + (size_t)i * W_) = v;
    }
}

extern "C" void kernel_launch(void* const* d_in, const int* in_sizes, int n_in,
                              void* d_out, int out_size, void* d_ws, size_t ws_size,
                              hipStream_t stream) {
    const float* x    = (const float*)d_in[0];
    const float* filt = (const float*)d_in[1];
    float* out = (float*)d_out;
    float* wsb = (float*)d_ws;          // one 64 MiB spare tensor
    const size_t N = (size_t)B_ * C_ * H_ * W_;

    float* S[8];
    for (int k = 0; k < 8; ++k) S[k] = out + (size_t)k * N;

    const dim3 grid(NPB);
    const dim3 block(512);

    auto launch = [&](const float* src, float* dst, int parity) {
        shear_sepconv_kernel<<<grid, block, 0, stream>>>(src, dst, filt, parity);
    };

    // Serial tree schedule (DFS) — keeps each 64MB producer->consumer pair L3-resident.
    launch(x,    wsb,  0);   // A
    launch(wsb,  S[7], 0);   // AA (S7 temp)
    launch(S[7], S[0], 0);   // out0
    launch(S[7], S[1], 1);   // out1
    launch(wsb,  S[7], 1);   // AB
    launch(S[7], S[2], 0);   // out2
    launch(S[7], S[3], 1);   // out3
    launch(x,    S[7], 1);   // B
    launch(S[7], wsb,  0);   // BA
    launch(wsb,  S[4], 0);   // out4
    launch(wsb,  S[5], 1);   // out5
    launch(S[7], wsb,  1);   // BB
    launch(wsb,  S[6], 0);   // out6
    launch(wsb,  S[7], 1);   // out7
}

// Round 3
// 619.629 us; speedup vs baseline: 1.2963x; 1.2963x over previous
//
#include <hip/hip_runtime.h>

// DirectionalFilterBank: 3-level binary tree of (shear ±1 -> depthwise 9x9 conv).
// shear(x,s)[h,w] = 0.5*(x[h,c0]+x[h,c0+1]), c0 = w + s*h + (s>0 ? -128 : 127),
// defined on w in [0,256); conv zero-pads the SHEARED image by 4 on all sides.
// Filter is rank-2 separable: filt_c = -(A (x) A) + (B (x) B) [+ center delta, c==0].
//
// Serial-14 schedule (keeps 64MB producer->consumer pairs L3-resident).
// R1 (best=590us): wave-per-row vectorized staging, TH=32, 256thr.
// R2 (FAILED, 803us): 512thr/6 waves-SIMD -> occupancy does NOT help; time tracked
// the +33% instruction count instead.
//
// Empirical law from R0/R1/R2: time ~ instructions x ~5 stall factor, occupancy-
// independent (17-20% issue efficiency at 3 AND 6 waves/SIMD). So THIS ROUND cuts
// instructions: TH=64 tile, 256 thr, wave w owns out rows [16w,16w+16), thread =
// 4 cols x 16 rows (window 24). Horizontal redundancy 1.6x -> 1.33x, staged halo
// 40/32 -> 72/64 rows, blocks 2048 -> 1024. Per-CU VALU and LDS instr both -21%.
// LDS 74.25 KB -> 2 blocks/CU (2 waves/SIMD) -- acceptable per R2's lesson.

#define B_ 4
#define C_ 64
#define H_ 256
#define W_ 256
#define TH 64                 // output rows per block
#define SROWS (TH + 8)        // 72 staged sheared rows
#define SCOLS (W_ + 8)        // 264 staged cols; LDS = 74.25 KiB
#define NPB 1024              // blocks per conv = 4*64*4

// 4-byte-aligned float4 view: shear offset makes global f4 loads dword- but not
// 16B-aligned. Compiler emits a legal unaligned dwordx4 (or split) load.
struct alignas(4) f4u { float x, y, z, w; };

__global__ __launch_bounds__(256) void shear_sepconv_kernel(
    const float* __restrict__ in, float* __restrict__ dst,
    const float* __restrict__ filt, int parity)
{
    __shared__ float s_sh[SROWS][SCOLS];

    const int tid  = threadIdx.x;
    const int bid  = (int)blockIdx.x;
    const int tile = bid & 3;            // H/TH = 4
    const int c    = (bid >> 2) & 63;    // C = 64
    const int b    = bid >> 8;
    const int h0   = tile * TH;
    const int sign = parity ? -1 : 1;
    const int off  = parity ? 127 : -128;

    const float* base = in + ((size_t)b * C_ + c) * (size_t)(H_ * W_);

    // ---- stage sheared rows h0-4 .. h0+67 ----
    // Wave w stages rows r = w + 4u, u = 0..17. Lane L produces sheared cols
    // 4L..4L+3 (stored at j = 4+4L) from x[c0..c0+4], c0 = off + sign*hr + 4L
    // (wave-uniform g = off + sign*hr). <=1 divergent lane per row.
    {
        const int wave = tid >> 6;       // 0..3
        const int lane = tid & 63;

        // halo cols j in [0,4) and [260,264) are always zero: 72 rows x 2 f4s
        if (tid < 144) {
            const int r = tid >> 1;
            *(float4*)&s_sh[r][(tid & 1) ? 260 : 0] = make_float4(0.f, 0.f, 0.f, 0.f);
        }

        #pragma unroll
        for (int u = 0; u < 18; ++u) {
            const int r  = wave + u * 4;
            const int hr = h0 + r - 4;
            float4 v = make_float4(0.f, 0.f, 0.f, 0.f);
            if ((unsigned)hr < 256u) {                       // wave-uniform
                const float* row = base + (size_t)hr * W_;
                const int c0 = off + sign * hr + lane * 4;
                if (c0 >= 0 && c0 <= 251) {                  // fast: fully interior
                    const f4u  a = *(const f4u*)(row + c0);
                    const float e = row[c0 + 4];
                    v.x = 0.5f * (a.x + a.y);
                    v.y = 0.5f * (a.y + a.z);
                    v.z = 0.5f * (a.z + a.w);
                    v.w = 0.5f * (a.w + e);
                } else if (c0 >= -4 && c0 < 256) {           // <=1 lane per row
                    float t0 = ((unsigned)(c0    ) < 256u) ? row[c0    ] : 0.f;
                    float t1 = ((unsigned)(c0 + 1) < 256u) ? row[c0 + 1] : 0.f;
                    float t2 = ((unsigned)(c0 + 2) < 256u) ? row[c0 + 2] : 0.f;
                    float t3 = ((unsigned)(c0 + 3) < 256u) ? row[c0 + 3] : 0.f;
                    float t4 = ((unsigned)(c0 + 4) < 256u) ? row[c0 + 4] : 0.f;
                    v.x = 0.5f * (t0 + t1);
                    v.y = 0.5f * (t1 + t2);
                    v.z = 0.5f * (t2 + t3);
                    v.w = 0.5f * (t3 + t4);
                }
                // else: fully outside -> zero
            }
            *(float4*)&s_sh[r][4 + lane * 4] = v;            // 16B-aligned
        }
    }

    // ---- separable factors from channel 1 (uniform; identical for all c) ----
    const float* f1 = filt + 81;
    const float A4  = sqrtf(fmaxf(-f1[4 * 9 + 4], 0.f));
    const float rA4 = 1.f / A4;
    const float A0  = -f1[0 * 9 + 4] * rA4;
    const float A2  = -f1[2 * 9 + 4] * rA4;
    const float A6  = -f1[6 * 9 + 4] * rA4;
    const float A8  = -f1[8 * 9 + 4] * rA4;
    const float B5  = sqrtf(fmaxf(f1[5 * 9 + 5], 0.f));
    const float rB5 = 1.f / B5;
    const float B1  = f1[1 * 9 + 5] * rB5;
    const float B3  = f1[3 * 9 + 5] * rB5;
    const float B7  = f1[7 * 9 + 5] * rB5;
    const float vc[9] = {-A0, B1, -A2, B3, -A4, B5, -A6, B7, -A8};

    __syncthreads();

    // ---- compute: wave w -> out rows [16w,16w+16); thread = 4 cols x 16 rows ----
    const int wv   = tid >> 6;           // 0..3
    const int lane = tid & 63;
    const int w0   = lane * 4;

    float acc[16][4];
    #pragma unroll
    for (int i = 0; i < 16; ++i)
        #pragma unroll
        for (int j = 0; j < 4; ++j) acc[i][j] = 0.f;

    #pragma unroll
    for (int t = 0; t < 24; ++t) {       // staged rows 16*wv + t
        const int rr = wv * 16 + t;
        const float4 sa = *(const float4*)&s_sh[rr][w0];
        const float4 sb = *(const float4*)&s_sh[rr][w0 + 4];
        const float4 sc4 = *(const float4*)&s_sh[rr][w0 + 8];
        const float s[12] = {sa.x, sa.y, sa.z, sa.w,
                             sb.x, sb.y, sb.z, sb.w,
                             sc4.x, sc4.y, sc4.z, sc4.w};
        float ha[4], hb[4];
        #pragma unroll
        for (int j = 0; j < 4; ++j) {
            ha[j] = fmaf(A8, s[j + 8],
                    fmaf(A6, s[j + 6],
                    fmaf(A4, s[j + 4],
                    fmaf(A2, s[j + 2], A0 * s[j]))));
            hb[j] = fmaf(B7, s[j + 7],
                    fmaf(B5, s[j + 5],
                    fmaf(B3, s[j + 3], B1 * s[j + 1])));
        }
        #pragma unroll
        for (int i = 0; i < 16; ++i) {
            const int ky = t - i;        // compile-time after unroll
            if (ky >= 0 && ky < 9) {
                #pragma unroll
                for (int j = 0; j < 4; ++j) {
                    const float hv = (ky & 1) ? hb[j] : ha[j];
                    acc[i][j] = fmaf(vc[ky], hv, acc[i][j]);
                }
            }
        }
    }

    // channel-0 delta: += sheared image value at the output location
    if (c == 0) {
        #pragma unroll
        for (int i = 0; i < 16; ++i) {
            const float4 sv = *(const float4*)&s_sh[wv * 16 + i + 4][w0 + 4];
            acc[i][0] += sv.x; acc[i][1] += sv.y; acc[i][2] += sv.z; acc[i][3] += sv.w;
        }
    }

    float* optr = dst + (((size_t)b * C_ + c) * H_ + h0 + wv * 16) * (size_t)W_ + w0;
    #pragma unroll
    for (int i = 0; i < 16; ++i) {
        const float4 v = {acc[i][0], acc[i][1], acc[i][2], acc[i][3]};
        *(float4*)(optr + (size_t)i * W_) = v;
    }
}

extern "C" void kernel_launch(void* const* d_in, const int* in_sizes, int n_in,
                              void* d_out, int out_size, void* d_ws, size_t ws_size,
                              hipStream_t stream) {
    const float* x    = (const float*)d_in[0];
    const float* filt = (const float*)d_in[1];
    float* out = (float*)d_out;
    float* wsb = (float*)d_ws;          // one 64 MiB spare tensor
    const size_t N = (size_t)B_ * C_ * H_ * W_;

    float* S[8];
    for (int k = 0; k < 8; ++k) S[k] = out + (size_t)k * N;

    const dim3 grid(NPB);
    const dim3 block(256);

    auto launch = [&](const float* src, float* dst, int parity) {
        shear_sepconv_kernel<<<grid, block, 0, stream>>>(src, dst, filt, parity);
    };

    // Serial tree schedule (DFS) — keeps each 64MB producer->consumer pair L3-resident.
    launch(x,    wsb,  0);   // A
    launch(wsb,  S[7], 0);   // AA (S7 temp)
    launch(S[7], S[0], 0);   // out0
    launch(S[7], S[1], 1);   // out1
    launch(wsb,  S[7], 1);   // AB
    launch(S[7], S[2], 0);   // out2
    launch(S[7], S[3], 1);   // out3
    launch(x,    S[7], 1);   // B
    launch(S[7], wsb,  0);   // BA
    launch(wsb,  S[4], 0);   // out4
    launch(wsb,  S[5], 1);   // out5
    launch(S[7], wsb,  1);   // BB
    launch(wsb,  S[6], 0);   // out6
    launch(wsb,  S[7], 1);   // out7
}

// Round 4
// 604.127 us; speedup vs baseline: 1.3295x; 1.0257x over previous
//
#include <hip/hip_runtime.h>

// DirectionalFilterBank: 3-level binary tree of (shear ±1 -> depthwise 9x9 conv).
// shear(x,s)[h,w] = 0.5*(x[h,c0]+x[h,c0+1]), c0 = w + s*h + (s>0 ? -128 : 127),
// defined on w in [0,256); conv zero-pads the SHEARED image by 4 on all sides.
// Filter is rank-2 separable: filt_c = -(A (x) A) + (B (x) B) [+ center delta, c==0].
//
// Model from R0-R3: time ~ instr x stall(waves/SIMD); stall ~5.2 at >=3 w/SIMD
// (R0,R1,R2), ~7 at 2 (R3). Keep R1 geometry (TH=32, 256thr, 41.25KB LDS, 3 blk/CU).
// R1 (best=590us): wave-per-row vectorized staging.
// R2 (803us): 512thr -> occupancy >3w/SIMD doesn't help. R3 (619us): 2w/SIMD hurts.
//
// THIS ROUND (two independent low-risk changes):
//  1. Staging explicitly two-phased in chunks of 5 rows: all 10 global loads issue
//     into registers BEFORE the 5 ds_writes (kills possible per-row L3 round-trip
//     serialization if the compiler wasn't hoisting loads past ds_writes).
//  2. Pair-batched launches 14 -> 7: each launch computes BOTH parities from one
//     shared source (grid 4096, k=bid>>11 selects parity+dst). Working set
//     64(src)+128(dsts) = 192MB <= 256MB L3 (full-level batching at 384+MB was
//     what thrashed). Saves ~6 kernel-boundary drains + launch gaps; both
//     parities read the same source tile while hot in the same XCD L2.

#define B_ 4
#define C_ 64
#define H_ 256
#define W_ 256
#define TH 32                 // output rows per block
#define SROWS (TH + 8)        // 40 staged sheared rows
#define SCOLS (W_ + 8)        // 264 staged cols; LDS = 41.25 KiB
#define NPB 2048              // blocks per (single) conv = 4*64*8

// 4-byte-aligned float4 view: shear offset makes global f4 loads dword- but not
// 16B-aligned. Compiler emits a legal unaligned dwordx4 (or split) load.
struct alignas(4) f4u { float x, y, z, w; };

__global__ __launch_bounds__(256) void shear_sepconv_pair(
    const float* __restrict__ in, float* __restrict__ dst0,
    float* __restrict__ dst1, const float* __restrict__ filt)
{
    __shared__ float s_sh[SROWS][SCOLS];

    const int tid   = threadIdx.x;
    const int bid   = (int)blockIdx.x;
    const int k     = bid >> 11;         // 0: parity +1 -> dst0, 1: parity -1 -> dst1
    const int inner = bid & 2047;
    const int tile  = inner & 7;         // H/TH = 8
    const int c     = (inner >> 3) & 63; // C = 64
    const int b     = inner >> 9;
    const int h0    = tile * TH;
    const int sign  = k ? -1 : 1;
    const int off   = k ? 127 : -128;
    float* dst      = k ? dst1 : dst0;

    const float* base = in + ((size_t)b * C_ + c) * (size_t)(H_ * W_);

    // ---- stage sheared rows h0-4 .. h0+35 ----
    // Wave w stages rows r = w + 4u, u = 0..9. Lane L produces sheared cols
    // 4L..4L+3 (stored at j = 4+4L) from x[c0..c0+4], c0 = off + sign*hr + 4L
    // (wave-uniform g = off + sign*hr). <=1 divergent lane per row.
    // Two-phase chunks of 5: all loads in flight before any ds_write.
    {
        const int wave = tid >> 6;
        const int lane = tid & 63;

        // halo cols j in [0,4) and [260,264) are always zero: 40 rows x 2 f4s
        if (tid < 80) {
            const int r = tid >> 1;
            *(float4*)&s_sh[r][(tid & 1) ? 260 : 0] = make_float4(0.f, 0.f, 0.f, 0.f);
        }

        #pragma unroll
        for (int ch = 0; ch < 2; ++ch) {
            f4u   a[5];
            float e[5];
            // phase 1: issue all global loads of this chunk into registers
            #pragma unroll
            for (int q = 0; q < 5; ++q) {
                a[q].x = a[q].y = a[q].z = a[q].w = 0.f; e[q] = 0.f;
                const int u  = ch * 5 + q;
                const int r  = wave + u * 4;
                const int hr = h0 + r - 4;
                if ((unsigned)hr < 256u) {                   // wave-uniform
                    const float* row = base + (size_t)hr * W_;
                    const int c0 = off + sign * hr + lane * 4;
                    if (c0 >= 0 && c0 <= 251) {              // fast: fully interior
                        a[q] = *(const f4u*)(row + c0);
                        e[q] = row[c0 + 4];
                    } else if (c0 >= -4 && c0 < 256) {       // <=1 lane per row
                        a[q].x = ((unsigned)(c0    ) < 256u) ? row[c0    ] : 0.f;
                        a[q].y = ((unsigned)(c0 + 1) < 256u) ? row[c0 + 1] : 0.f;
                        a[q].z = ((unsigned)(c0 + 2) < 256u) ? row[c0 + 2] : 0.f;
                        a[q].w = ((unsigned)(c0 + 3) < 256u) ? row[c0 + 3] : 0.f;
                        e[q]   = ((unsigned)(c0 + 4) < 256u) ? row[c0 + 4] : 0.f;
                    }
                    // else: fully outside -> zeros
                }
            }
            // phase 2: average + LDS writes
            #pragma unroll
            for (int q = 0; q < 5; ++q) {
                const int u = ch * 5 + q;
                const int r = wave + u * 4;
                float4 v;
                v.x = 0.5f * (a[q].x + a[q].y);
                v.y = 0.5f * (a[q].y + a[q].z);
                v.z = 0.5f * (a[q].z + a[q].w);
                v.w = 0.5f * (a[q].w + e[q]);
                *(float4*)&s_sh[r][4 + lane * 4] = v;        // 16B-aligned
            }
        }
    }

    // ---- separable factors from channel 1 (uniform; identical for all c) ----
    const float* f1 = filt + 81;
    const float A4  = sqrtf(fmaxf(-f1[4 * 9 + 4], 0.f));
    const float rA4 = 1.f / A4;
    const float A0  = -f1[0 * 9 + 4] * rA4;
    const float A2  = -f1[2 * 9 + 4] * rA4;
    const float A6  = -f1[6 * 9 + 4] * rA4;
    const float A8  = -f1[8 * 9 + 4] * rA4;
    const float B5  = sqrtf(fmaxf(f1[5 * 9 + 5], 0.f));
    const float rB5 = 1.f / B5;
    const float B1  = f1[1 * 9 + 5] * rB5;
    const float B3  = f1[3 * 9 + 5] * rB5;
    const float B7  = f1[7 * 9 + 5] * rB5;
    const float vc[9] = {-A0, B1, -A2, B3, -A4, B5, -A6, B7, -A8};

    __syncthreads();

    // ---- compute: 4 row-groups x 8 rows; thread = 4 cols x 8 rows (window 16) ----
    const int rg   = tid >> 6;           // 0..3 -> out rows rg*8 .. rg*8+7
    const int lane = tid & 63;
    const int w0   = lane * 4;

    float acc[8][4];
    #pragma unroll
    for (int i = 0; i < 8; ++i)
        #pragma unroll
        for (int j = 0; j < 4; ++j) acc[i][j] = 0.f;

    #pragma unroll
    for (int t = 0; t < 16; ++t) {       // staged rows rg*8 + t
        const int rr = rg * 8 + t;
        const float4 sa = *(const float4*)&s_sh[rr][w0];
        const float4 sb = *(const float4*)&s_sh[rr][w0 + 4];
        const float4 sc4 = *(const float4*)&s_sh[rr][w0 + 8];
        const float s[12] = {sa.x, sa.y, sa.z, sa.w,
                             sb.x, sb.y, sb.z, sb.w,
                             sc4.x, sc4.y, sc4.z, sc4.w};
        float ha[4], hb[4];
        #pragma unroll
        for (int j = 0; j < 4; ++j) {
            ha[j] = fmaf(A8, s[j + 8],
                    fmaf(A6, s[j + 6],
                    fmaf(A4, s[j + 4],
                    fmaf(A2, s[j + 2], A0 * s[j]))));
            hb[j] = fmaf(B7, s[j + 7],
                    fmaf(B5, s[j + 5],
                    fmaf(B3, s[j + 3], B1 * s[j + 1])));
        }
        #pragma unroll
        for (int i = 0; i < 8; ++i) {
            const int ky = t - i;        // compile-time after unroll
            if (ky >= 0 && ky < 9) {
                #pragma unroll
                for (int j = 0; j < 4; ++j) {
                    const float hv = (ky & 1) ? hb[j] : ha[j];
                    acc[i][j] = fmaf(vc[ky], hv, acc[i][j]);
                }
            }
        }
    }

    // channel-0 delta: += sheared image value at the output location
    if (c == 0) {
        #pragma unroll
        for (int i = 0; i < 8; ++i) {
            const float4 sv = *(const float4*)&s_sh[rg * 8 + i + 4][w0 + 4];
            acc[i][0] += sv.x; acc[i][1] += sv.y; acc[i][2] += sv.z; acc[i][3] += sv.w;
        }
    }

    float* optr = dst + (((size_t)b * C_ + c) * H_ + h0 + rg * 8) * (size_t)W_ + w0;
    #pragma unroll
    for (int i = 0; i < 8; ++i) {
        const float4 v = {acc[i][0], acc[i][1], acc[i][2], acc[i][3]};
        *(float4*)(optr + (size_t)i * W_) = v;
    }
}

extern "C" void kernel_launch(void* const* d_in, const int* in_sizes, int n_in,
                              void* d_out, int out_size, void* d_ws, size_t ws_size,
                              hipStream_t stream) {
    const float* x    = (const float*)d_in[0];
    const float* filt = (const float*)d_in[1];
    float* out = (float*)d_out;
    float* wsb = (float*)d_ws;          // one 64 MiB spare tensor
    const size_t N = (size_t)B_ * C_ * H_ * W_;

    float* S[8];
    for (int kk = 0; kk < 8; ++kk) S[kk] = out + (size_t)kk * N;

    const dim3 grid(2 * NPB);           // both parities in one launch
    const dim3 block(256);

    auto pair = [&](const float* src, float* d0, float* d1) {
        shear_sepconv_pair<<<grid, block, 0, stream>>>(src, d0, d1, filt);
    };

    // Pair-batched tree (7 launches). Each launch: src(64MB) + 2 dsts(128MB)
    // = 192MB working set, L3-resident. Order respects deps and buffer reuse.
    pair(x,    wsb,  S[7]);   // A=wsb,  B=S7
    pair(wsb,  S[6], S[5]);   // AA=S6,  AB=S5
    pair(S[6], S[0], S[1]);   // out0, out1
    pair(S[5], S[2], S[3]);   // out2, out3
    pair(S[7], S[6], wsb);    // BA=S6,  BB=wsb   (S6, wsb free by now)
    pair(S[6], S[4], S[5]);   // out4, out5      (S5 free)
    pair(wsb,  S[6], S[7]);   // out6, out7      (S6, S7 free)
}

// Round 5
// 497.876 us; speedup vs baseline: 1.6133x; 1.2134x over previous
//
#include <hip/hip_runtime.h>

// DirectionalFilterBank: 3-level binary tree of (shear ±1 -> depthwise 9x9 conv).
// shear(x,s)[h,w] = 0.5*(x[h,c0]+x[h,c0+1]), c0 = w + s*h + (s>0 ? -128 : 127),
// defined on w in [0,256); conv zero-pads the SHEARED image by 4 on all sides.
// Filter is rank-2 separable: filt_c = -(A (x) A) + (B (x) B) [+ center delta, c==0].
//
// Model from R0-R4: time ~ instr x ~4.5-5x stall, flat at >=3 blocks/CU (R2: 6
// waves/SIMD no help), worse at 2 (R3: +33%). Launch pairing + 2-phase staging:
// neutral (R4). Structural audits (fusion, sliding-window, shear commutation,
// global_load_lds) all lose by arithmetic -> keep R1 geometry: TH=32, 256 thr,
// 41.25KB LDS (3 blocks/CU), serial-14 DFS schedule (L3-resident pairs).
//
// THIS ROUND (instr trim + scheduler hint):
//  1. Branchless staging: the old interior/boundary dual path executed BOTH paths
//     nearly every row (every sheared span straddles [0,256)). Now one uniform
//     path: 5 clamped unconditional loads (v_med3 idiom) + 5 cndmask zeros.
//     ~40 -> ~30 wave-instr per staged row, no divergence, identical arithmetic.
//  2. s_setprio(1) around the compute FMA loop: 3 phase-staggered blocks/CU give
//     wave role-diversity (staging vs compute) -- the regime where setprio helps.

#define B_ 4
#define C_ 64
#define H_ 256
#define W_ 256
#define TH 32                 // output rows per block
#define SROWS (TH + 8)        // 40 staged sheared rows
#define SCOLS (W_ + 8)        // 264 staged cols; LDS = 41.25 KiB
#define NPB 2048              // blocks per conv = 4*64*8

__global__ __launch_bounds__(256) void shear_sepconv_kernel(
    const float* __restrict__ in, float* __restrict__ dst,
    const float* __restrict__ filt, int parity)
{
    __shared__ float s_sh[SROWS][SCOLS];

    const int tid  = threadIdx.x;
    const int bid  = (int)blockIdx.x;
    const int tile = bid & 7;            // H/TH = 8
    const int c    = (bid >> 3) & 63;    // C = 64
    const int b    = bid >> 9;
    const int h0   = tile * TH;
    const int sign = parity ? -1 : 1;
    const int off  = parity ? 127 : -128;

    const float* base = in + ((size_t)b * C_ + c) * (size_t)(H_ * W_);

    // ---- stage sheared rows h0-4 .. h0+35 ----
    // Wave w stages rows r = w + 4u, u = 0..9. Lane L produces sheared cols
    // 4L..4L+3 (stored at j = 4+4L) from x[c0..c0+4], c0 = off + sign*hr + 4L.
    // Branchless: clamped addresses (always legal) + per-element zero masks.
    {
        const int wave = tid >> 6;
        const int lane = tid & 63;

        // halo cols j in [0,4) and [260,264) are always zero: 40 rows x 2 f4s
        if (tid < 80) {
            const int r = tid >> 1;
            *(float4*)&s_sh[r][(tid & 1) ? 260 : 0] = make_float4(0.f, 0.f, 0.f, 0.f);
        }

        #pragma unroll
        for (int u = 0; u < 10; ++u) {
            const int r  = wave + u * 4;
            const int hr = h0 + r - 4;
            float4 v = make_float4(0.f, 0.f, 0.f, 0.f);
            if ((unsigned)hr < 256u) {                   // wave-coherent branch
                const float* row = base + (size_t)hr * W_;
                const int c0 = off + sign * hr + lane * 4;
                const int i0 = min(max(c0,     0), 255); // v_med3 clamp idiom
                const int i1 = min(max(c0 + 1, 0), 255);
                const int i2 = min(max(c0 + 2, 0), 255);
                const int i3 = min(max(c0 + 3, 0), 255);
                const int i4 = min(max(c0 + 4, 0), 255);
                float t0 = row[i0];
                float t1 = row[i1];
                float t2 = row[i2];
                float t3 = row[i3];
                float t4 = row[i4];
                t0 = ((unsigned)c0       < 256u) ? t0 : 0.f;
                t1 = ((unsigned)(c0 + 1) < 256u) ? t1 : 0.f;
                t2 = ((unsigned)(c0 + 2) < 256u) ? t2 : 0.f;
                t3 = ((unsigned)(c0 + 3) < 256u) ? t3 : 0.f;
                t4 = ((unsigned)(c0 + 4) < 256u) ? t4 : 0.f;
                v.x = 0.5f * (t0 + t1);
                v.y = 0.5f * (t1 + t2);
                v.z = 0.5f * (t2 + t3);
                v.w = 0.5f * (t3 + t4);
            }
            *(float4*)&s_sh[r][4 + lane * 4] = v;        // 16B-aligned
        }
    }

    // ---- separable factors from channel 1 (uniform; identical for all c) ----
    const float* f1 = filt + 81;
    const float A4  = sqrtf(fmaxf(-f1[4 * 9 + 4], 0.f));
    const float rA4 = 1.f / A4;
    const float A0  = -f1[0 * 9 + 4] * rA4;
    const float A2  = -f1[2 * 9 + 4] * rA4;
    const float A6  = -f1[6 * 9 + 4] * rA4;
    const float A8  = -f1[8 * 9 + 4] * rA4;
    const float B5  = sqrtf(fmaxf(f1[5 * 9 + 5], 0.f));
    const float rB5 = 1.f / B5;
    const float B1  = f1[1 * 9 + 5] * rB5;
    const float B3  = f1[3 * 9 + 5] * rB5;
    const float B7  = f1[7 * 9 + 5] * rB5;
    const float vc[9] = {-A0, B1, -A2, B3, -A4, B5, -A6, B7, -A8};

    __syncthreads();

    // ---- compute: 4 row-groups x 8 rows; thread = 4 cols x 8 rows (window 16) ----
    const int rg   = tid >> 6;           // 0..3 -> out rows rg*8 .. rg*8+7
    const int lane = tid & 63;
    const int w0   = lane * 4;

    float acc[8][4];
    #pragma unroll
    for (int i = 0; i < 8; ++i)
        #pragma unroll
        for (int j = 0; j < 4; ++j) acc[i][j] = 0.f;

    __builtin_amdgcn_s_setprio(1);
    #pragma unroll
    for (int t = 0; t < 16; ++t) {       // staged rows rg*8 + t
        const int rr = rg * 8 + t;
        const float4 sa = *(const float4*)&s_sh[rr][w0];
        const float4 sb = *(const float4*)&s_sh[rr][w0 + 4];
        const float4 sc4 = *(const float4*)&s_sh[rr][w0 + 8];
        const float s[12] = {sa.x, sa.y, sa.z, sa.w,
                             sb.x, sb.y, sb.z, sb.w,
                             sc4.x, sc4.y, sc4.z, sc4.w};
        float ha[4], hb[4];
        #pragma unroll
        for (int j = 0; j < 4; ++j) {
            ha[j] = fmaf(A8, s[j + 8],
                    fmaf(A6, s[j + 6],
                    fmaf(A4, s[j + 4],
                    fmaf(A2, s[j + 2], A0 * s[j]))));
            hb[j] = fmaf(B7, s[j + 7],
                    fmaf(B5, s[j + 5],
                    fmaf(B3, s[j + 3], B1 * s[j + 1])));
        }
        #pragma unroll
        for (int i = 0; i < 8; ++i) {
            const int ky = t - i;        // compile-time after unroll
            if (ky >= 0 && ky < 9) {
                #pragma unroll
                for (int j = 0; j < 4; ++j) {
                    const float hv = (ky & 1) ? hb[j] : ha[j];
                    acc[i][j] = fmaf(vc[ky], hv, acc[i][j]);
                }
            }
        }
    }
    __builtin_amdgcn_s_setprio(0);

    // channel-0 delta: += sheared image value at the output location
    if (c == 0) {
        #pragma unroll
        for (int i = 0; i < 8; ++i) {
            const float4 sv = *(const float4*)&s_sh[rg * 8 + i + 4][w0 + 4];
            acc[i][0] += sv.x; acc[i][1] += sv.y; acc[i][2] += sv.z; acc[i][3] += sv.w;
        }
    }

    float* optr = dst + (((size_t)b * C_ + c) * H_ + h0 + rg * 8) * (size_t)W_ + w0;
    #pragma unroll
    for (int i = 0; i < 8; ++i) {
        const float4 v = {acc[i][0], acc[i][1], acc[i][2], acc[i][3]};
        *(float4*)(optr + (size_t)i * W_) = v;
    }
}

extern "C" void kernel_launch(void* const* d_in, const int* in_sizes, int n_in,
                              void* d_out, int out_size, void* d_ws, size_t ws_size,
                              hipStream_t stream) {
    const float* x    = (const float*)d_in[0];
    const float* filt = (const float*)d_in[1];
    float* out = (float*)d_out;
    float* wsb = (float*)d_ws;          // one 64 MiB spare tensor
    const size_t N = (size_t)B_ * C_ * H_ * W_;

    float* S[8];
    for (int k = 0; k < 8; ++k) S[k] = out + (size_t)k * N;

    const dim3 grid(NPB);
    const dim3 block(256);

    auto launch = [&](const float* src, float* dst, int parity) {
        shear_sepconv_kernel<<<grid, block, 0, stream>>>(src, dst, filt, parity);
    };

    // Serial tree schedule (DFS) — keeps each 64MB producer->consumer pair L3-resident.
    launch(x,    wsb,  0);   // A
    launch(wsb,  S[7], 0);   // AA (S7 temp)
    launch(S[7], S[0], 0);   // out0
    launch(S[7], S[1], 1);   // out1
    launch(wsb,  S[7], 1);   // AB
    launch(S[7], S[2], 0);   // out2
    launch(S[7], S[3], 1);   // out3
    launch(x,    S[7], 1);   // B
    launch(S[7], wsb,  0);   // BA
    launch(wsb,  S[4], 0);   // out4
    launch(wsb,  S[5], 1);   // out5
    launch(S[7], wsb,  1);   // BB
    launch(wsb,  S[6], 0);   // out6
    launch(wsb,  S[7], 1);   // out7
}

// Round 6
// 488.482 us; speedup vs baseline: 1.6443x; 1.0192x over previous
//
#include <hip/hip_runtime.h>

// DirectionalFilterBank: 3-level binary tree of (shear ±1 -> depthwise 9x9 conv).
// shear(x,s)[h,w] = 0.5*(x[h,c0]+x[h,c0+1]), c0 = w + s*h + (s>0 ? -128 : 127),
// w in [0,256); conv zero-pads the SHEARED image by 4. Filter rank-2 separable:
// filt_c = -(A (x) A) + (B (x) B) [+ center delta, c==0].
//
// Model R0-R5: time ~ instr, amplified when trims also cut loads/divergence;
// occupancy flat >=3 blk/CU (R2), worse at 2 (R3). R5 (498us): branchless staging
// + setprio. Geometry: TH=32, 256thr, 41.25KB LDS, serial DFS (L3-resident pairs).
//
// THIS ROUND: PADDED INTERMEDIATES. 12/14 convs read buffers we produce; store
// them with stride 260 (cols -4..259 zero-padded; right-pad of row hr == left-pad
// of row hr+1, so 260 suffices). Padded-src staging: 1 clamp + 1 unaligned-f4 +
// 1 scalar load + 4 cndmask + 4 FMA (~17 instr/row vs ~30; 2 loads vs 5).
// Padded buf = 65MiB+16B > 64MiB ws -> padded temps live in not-yet-written out
// slots. Schedule verified byte-range by byte-range (B-subtree first):
//   RB=[0,66MiB) RBA=[66,132) RA=[132,198); AA->wsb, AB->out[0,64) unpadded.
//   B(RB,p1) BA(RBA,p0) out4 out5 BB(RBA,p1) out6 out7 | A(RA,p0) AA(wsb,p0)
//   AB(ABs,p1) out2 out3 out0 out1.  No read/write overlap in any launch; no
//   final overwritten after write. Producers write their own halo zeros.

#define B_ 4
#define C_ 64
#define H_ 256
#define W_ 256
#define TH 32                 // output rows per block
#define SROWS (TH + 8)        // 40 staged sheared rows
#define SCOLS (W_ + 8)        // 264 staged cols; LDS = 41.25 KiB
#define NPB 2048              // blocks per conv = 4*64*8
#define PSTRIDE 260           // padded row stride (floats), cols -4..255 (+shared)
#define PPLANE (H_ * PSTRIDE) // padded plane floats

// 4-byte-aligned float4 view (shear loads are dword- but not 16B-aligned).
struct alignas(4) f4u { float x, y, z, w; };

template<bool SRC_PAD, bool DST_PAD>
__global__ __launch_bounds__(256) void shear_sepconv_kernel(
    const float* __restrict__ in, float* __restrict__ dst,
    const float* __restrict__ filt, int parity)
{
    __shared__ float s_sh[SROWS][SCOLS];

    const int tid  = threadIdx.x;
    const int bid  = (int)blockIdx.x;
    const int tile = bid & 7;            // H/TH = 8
    const int c    = (bid >> 3) & 63;    // C = 64
    const int b    = bid >> 9;
    const int h0   = tile * TH;
    const int sign = parity ? -1 : 1;
    const int off  = parity ? 127 : -128;

    const int plane_idx = b * C_ + c;
    const float* base = in + (size_t)plane_idx * (size_t)(SRC_PAD ? PPLANE : H_ * W_);

    // ---- stage sheared rows h0-4 .. h0+35 (wave w: rows w+4u, lane: 4 cols) ----
    {
        const int wave = tid >> 6;
        const int lane = tid & 63;

        // LDS halo cols [0,4) and [260,264) are always zero
        if (tid < 80) {
            const int r = tid >> 1;
            *(float4*)&s_sh[r][(tid & 1) ? 260 : 0] = make_float4(0.f, 0.f, 0.f, 0.f);
        }

        #pragma unroll
        for (int u = 0; u < 10; ++u) {
            const int r  = wave + u * 4;
            const int hr = h0 + r - 4;
            float4 v = make_float4(0.f, 0.f, 0.f, 0.f);
            if ((unsigned)hr < 256u) {                   // wave-coherent
                if (SRC_PAD) {
                    // padded source: value(hr,w) = row[w+4], legal for w in [-4,259]
                    const float* row = base + (size_t)hr * PSTRIDE;
                    const int d  = off + sign * hr + 4 + lane * 4;  // c0+4
                    const int dc = min(max(d, 0), 259);
                    const bool valid = (unsigned)d < 260u;          // c0 in [-4,255]
                    const f4u  a = *(const f4u*)(row + dc);
                    const float e = row[dc + 4];                    // <= row+263, legal
                    v.x = valid ? 0.5f * (a.x + a.y) : 0.f;
                    v.y = valid ? 0.5f * (a.y + a.z) : 0.f;
                    v.z = valid ? 0.5f * (a.z + a.w) : 0.f;
                    v.w = valid ? 0.5f * (a.w + e)   : 0.f;
                } else {
                    // unpadded source: branchless clamp + per-element zero masks
                    const float* row = base + (size_t)hr * W_;
                    const int c0 = off + sign * hr + lane * 4;
                    const int i0 = min(max(c0,     0), 255);
                    const int i1 = min(max(c0 + 1, 0), 255);
                    const int i2 = min(max(c0 + 2, 0), 255);
                    const int i3 = min(max(c0 + 3, 0), 255);
                    const int i4 = min(max(c0 + 4, 0), 255);
                    float t0 = row[i0];
                    float t1 = row[i1];
                    float t2 = row[i2];
                    float t3 = row[i3];
                    float t4 = row[i4];
                    t0 = ((unsigned)c0       < 256u) ? t0 : 0.f;
                    t1 = ((unsigned)(c0 + 1) < 256u) ? t1 : 0.f;
                    t2 = ((unsigned)(c0 + 2) < 256u) ? t2 : 0.f;
                    t3 = ((unsigned)(c0 + 3) < 256u) ? t3 : 0.f;
                    t4 = ((unsigned)(c0 + 4) < 256u) ? t4 : 0.f;
                    v.x = 0.5f * (t0 + t1);
                    v.y = 0.5f * (t1 + t2);
                    v.z = 0.5f * (t2 + t3);
                    v.w = 0.5f * (t3 + t4);
                }
            }
            *(float4*)&s_sh[r][4 + lane * 4] = v;        // 16B-aligned
        }
    }

    // ---- separable factors from channel 1 (uniform; identical for all c) ----
    const float* f1 = filt + 81;
    const float A4  = sqrtf(fmaxf(-f1[4 * 9 + 4], 0.f));
    const float rA4 = 1.f / A4;
    const float A0  = -f1[0 * 9 + 4] * rA4;
    const float A2  = -f1[2 * 9 + 4] * rA4;
    const float A6  = -f1[6 * 9 + 4] * rA4;
    const float A8  = -f1[8 * 9 + 4] * rA4;
    const float B5  = sqrtf(fmaxf(f1[5 * 9 + 5], 0.f));
    const float rB5 = 1.f / B5;
    const float B1  = f1[1 * 9 + 5] * rB5;
    const float B3  = f1[3 * 9 + 5] * rB5;
    const float B7  = f1[7 * 9 + 5] * rB5;
    const float vc[9] = {-A0, B1, -A2, B3, -A4, B5, -A6, B7, -A8};

    __syncthreads();

    // ---- compute: 4 row-groups x 8 rows; thread = 4 cols x 8 rows (window 16) ----
    const int rg   = tid >> 6;           // 0..3 -> out rows rg*8 .. rg*8+7
    const int lane = tid & 63;
    const int w0   = lane * 4;

    float acc[8][4];
    #pragma unroll
    for (int i = 0; i < 8; ++i)
        #pragma unroll
        for (int j = 0; j < 4; ++j) acc[i][j] = 0.f;

    __builtin_amdgcn_s_setprio(1);
    #pragma unroll
    for (int t = 0; t < 16; ++t) {       // staged rows rg*8 + t
        const int rr = rg * 8 + t;
        const float4 sa = *(const float4*)&s_sh[rr][w0];
        const float4 sb = *(const float4*)&s_sh[rr][w0 + 4];
        const float4 sc4 = *(const float4*)&s_sh[rr][w0 + 8];
        const float s[12] = {sa.x, sa.y, sa.z, sa.w,
                             sb.x, sb.y, sb.z, sb.w,
                             sc4.x, sc4.y, sc4.z, sc4.w};
        float ha[4], hb[4];
        #pragma unroll
        for (int j = 0; j < 4; ++j) {
            ha[j] = fmaf(A8, s[j + 8],
                    fmaf(A6, s[j + 6],
                    fmaf(A4, s[j + 4],
                    fmaf(A2, s[j + 2], A0 * s[j]))));
            hb[j] = fmaf(B7, s[j + 7],
                    fmaf(B5, s[j + 5],
                    fmaf(B3, s[j + 3], B1 * s[j + 1])));
        }
        #pragma unroll
        for (int i = 0; i < 8; ++i) {
            const int ky = t - i;        // compile-time after unroll
            if (ky >= 0 && ky < 9) {
                #pragma unroll
                for (int j = 0; j < 4; ++j) {
                    const float hv = (ky & 1) ? hb[j] : ha[j];
                    acc[i][j] = fmaf(vc[ky], hv, acc[i][j]);
                }
            }
        }
    }
    __builtin_amdgcn_s_setprio(0);

    // channel-0 delta: += sheared image value at the output location
    if (c == 0) {
        #pragma unroll
        for (int i = 0; i < 8; ++i) {
            const float4 sv = *(const float4*)&s_sh[rg * 8 + i + 4][w0 + 4];
            acc[i][0] += sv.x; acc[i][1] += sv.y; acc[i][2] += sv.z; acc[i][3] += sv.w;
        }
    }

    if (DST_PAD) {
        float* plane = dst + (size_t)plane_idx * PPLANE;
        // halo: zero right-pad of each owned row == left-pad of next row
        if (lane < 8)
            *(float4*)(plane + (size_t)(h0 + rg * 8 + lane + 1) * PSTRIDE) =
                make_float4(0.f, 0.f, 0.f, 0.f);
        if (bid == 0 && tid == 8)        // very first plane's row-0 left pad
            *(float4*)dst = make_float4(0.f, 0.f, 0.f, 0.f);
        float* optr = plane + (size_t)(h0 + rg * 8) * PSTRIDE + 4 + w0;
        #pragma unroll
        for (int i = 0; i < 8; ++i) {
            const float4 v = {acc[i][0], acc[i][1], acc[i][2], acc[i][3]};
            *(float4*)(optr + (size_t)i * PSTRIDE) = v;  // 16B-aligned (1040%16==0)
        }
    } else {
        float* optr = dst + (((size_t)plane_idx) * H_ + h0 + rg * 8) * (size_t)W_ + w0;
        #pragma unroll
        for (int i = 0; i < 8; ++i) {
            const float4 v = {acc[i][0], acc[i][1], acc[i][2], acc[i][3]};
            *(float4*)(optr + (size_t)i * W_) = v;
        }
    }
}

extern "C" void kernel_launch(void* const* d_in, const int* in_sizes, int n_in,
                              void* d_out, int out_size, void* d_ws, size_t ws_size,
                              hipStream_t stream) {
    const float* x    = (const float*)d_in[0];
    const float* filt = (const float*)d_in[1];
    float* out = (float*)d_out;
    float* wsb = (float*)d_ws;          // 64 MiB spare: AA (unpadded) lives here
    const size_t N = (size_t)B_ * C_ * H_ * W_;   // floats per 64MiB slot

    float* S[8];
    for (int k = 0; k < 8; ++k) S[k] = out + (size_t)k * N;

    // Padded scratch regions inside out (66MiB spacing; padded buf = 65MiB+16B).
    float* RB  = out;                                   // [  0, 66) MiB
    float* RBA = out + ((size_t)66 << 20) / 4;          // [ 66,132) MiB
    float* RA  = out + ((size_t)132 << 20) / 4;         // [132,198) MiB
    float* ABs = out;                                   // [  0, 64) MiB, after RB dead

    const dim3 grid(NPB);
    const dim3 block(256);

    #define L(SP, DP, src, dst, par) \
        shear_sepconv_kernel<SP, DP><<<grid, block, 0, stream>>>(src, dst, filt, par)

    // Phase 1: B-subtree (finals out4..7 in [256,512)MiB, disjoint from scratch)
    L(false, true , x,   RB,   1);   // B  = shear(-1) conv, padded
    L(true , true , RB,  RBA,  0);   // BA, padded
    L(true , false, RBA, S[4], 0);   // out4
    L(true , false, RBA, S[5], 1);   // out5
    L(true , true , RB,  RBA,  1);   // BB, padded (BA dead)
    L(true , false, RBA, S[6], 0);   // out6
    L(true , false, RBA, S[7], 1);   // out7
    // Phase 2: A-subtree (RB/RBA dead; RA overlaps out2/3 slots, dead before writes)
    L(false, true , x,   RA,   0);   // A, padded
    L(true , false, RA,  wsb,  0);   // AA, unpadded -> ws
    L(true , false, RA,  ABs,  1);   // AB, unpadded -> [0,64)MiB (RB dead)
    L(false, false, ABs, S[2], 0);   // out2 (masked read)
    L(false, false, ABs, S[3], 1);   // out3
    L(false, false, wsb, S[0], 0);   // out0 (overwrites ABs, dead)
    L(false, false, wsb, S[1], 1);   // out1
    #undef L
}